// Round 6
// baseline (8390.790 us; speedup 1.0000x reference)
//
#include <hip/hip_runtime.h>
#include <hip/hip_bf16.h>

// Problem constants
#define T_ 512
#define B_ 64
#define I_ 256
#define H_ 512
#define O_ 256
#define NGB 32              // gate blocks: 4 domains x 8 blocks (64 h-cols each)
#define NLB 8               // linear blocks: 4 domains x 2 (128 out-cols each)
#define NBLK (NGB + NLB)
#define NTHR 512
#define NTOT (NBLK * NTHR)

typedef unsigned short u16;
typedef unsigned int u32;
typedef unsigned long long u64;
typedef short bf16x8 __attribute__((ext_vector_type(8)));   // 16 B = 4 VGPRs
typedef float f32x4 __attribute__((ext_vector_type(4)));
typedef u32 u32x4 __attribute__((ext_vector_type(4)));

// ---- control block (bytes 0..4095 of ws, zeroed by init_cnt) ----
#define CT_LIN   0         // u32 linf[8]: linear block (mt,q) consumed h2{linf}
#define CT_B0    64        // one-time init barrier counter

// ---- workspace layout (bytes) ----
#define WS_XBF   4096
#define WS_WHH1  (WS_XBF   + 16777216)
#define WS_WIH1  (WS_WHH1  + 2097152)
#define WS_WIH2  (WS_WIH1  + 1048576)
#define WS_WHH2  (WS_WIH2  + 2097152)
#define WS_WLIN  (WS_WHH2  + 2097152)
#define WS_B1    (WS_WLIN  + 262144)
#define WS_B2    (WS_B1    + 8192)
// tagged h rings: word = (tag<<16) | bf16(h). tile = (slot,mt): 16 rows x 512 u32
#define WS_H1T   (WS_B2    + 8192)      // 2 slots x 4 domains x 8192 u32 = 262144 B
#define WS_H2T   (WS_H1T   + 262144)    // 4 slots x 4 domains x 8192 u32 = 524288 B
#define WS_END   (WS_H2T   + 524288)

__device__ __forceinline__ u16 f2bf(float f) {
  union { float f; unsigned u; } v; v.f = f;
  unsigned r = v.u + 0x7FFFu + ((v.u >> 16) & 1u);
  return (u16)(r >> 16);
}
__device__ __forceinline__ float sigm(float x)  { return 1.0f / (1.0f + __expf(-x)); }
__device__ __forceinline__ float tanh_(float x) { return 1.0f - 2.0f / (__expf(2.0f * x) + 1.0f); }
__device__ __forceinline__ bf16x8 ldg8(const u16* p) { return *(const bf16x8*)p; }
__device__ __forceinline__ void ast32(u32* p, u32 v) {
  __hip_atomic_store(p, v, __ATOMIC_RELAXED, __HIP_MEMORY_SCOPE_AGENT);
}
#define MFMA16(a, b, c) __builtin_amdgcn_mfma_f32_16x16x32_bf16((a), (b), (c), 0, 0, 0)

__device__ __forceinline__ void cvt8(const float* s, u16* dst) {
  bf16x8 v;
  #pragma unroll
  for (int jj = 0; jj < 8; jj++) v[jj] = (short)f2bf(s[jj]);
  *(bf16x8*)dst = v;
}

// ============ 2-deep rolling poll machinery (round-6) ============
// Batch = 4x global_load_dwordx4 sc0 sc1 (64B/lane, LLC-coherent), +1 dword for
// the decoder's back-pressure word. Two batches in flight; s_waitcnt vmcnt(4|5)
// waits for exactly the OLDER batch (vmcnt retires in issue order, so any
// unrelated residue issued earlier is also covered). "+v" ties on the waits
// stop the compiler hoisting register reads above the waitcnt (rule-#18).
// On hit we exit with <=1 batch in flight; PDRAIN* (vmcnt(0) + liveness pins)
// retires it later, off the critical path.
#define PISSF(A,B,C,D,P) asm volatile( \
  "global_load_dwordx4 %0, %4, off sc0 sc1\n\t" \
  "global_load_dwordx4 %1, %4, off offset:16 sc0 sc1\n\t" \
  "global_load_dwordx4 %2, %4, off offset:32 sc0 sc1\n\t" \
  "global_load_dwordx4 %3, %4, off offset:48 sc0 sc1" \
  : "=&v"(A), "=&v"(B), "=&v"(C), "=&v"(D) : "v"(P) : "memory")

#define PISSL(A,B,C,D,L,P,Q) asm volatile( \
  "global_load_dwordx4 %0, %5, off sc0 sc1\n\t" \
  "global_load_dwordx4 %1, %5, off offset:16 sc0 sc1\n\t" \
  "global_load_dwordx4 %2, %5, off offset:32 sc0 sc1\n\t" \
  "global_load_dwordx4 %3, %5, off offset:48 sc0 sc1\n\t" \
  "global_load_dword   %4, %6, off sc0 sc1" \
  : "=&v"(A), "=&v"(B), "=&v"(C), "=&v"(D), "=&v"(L) : "v"(P), "v"(Q) : "memory")

#define PWAITF(A,B,C,D) asm volatile("s_waitcnt vmcnt(4)" \
  : "+v"(A), "+v"(B), "+v"(C), "+v"(D) :: "memory")
#define PWAITL(A,B,C,D,L) asm volatile("s_waitcnt vmcnt(5)" \
  : "+v"(A), "+v"(B), "+v"(C), "+v"(D), "+v"(L) :: "memory")

#define PDRAIN8(A0,B0,C0,D0,A1,B1,C1,D1) asm volatile("s_waitcnt vmcnt(0)" \
  :: "v"(A0),"v"(B0),"v"(C0),"v"(D0),"v"(A1),"v"(B1),"v"(C1),"v"(D1) : "memory")
#define PDRAINL(A0,B0,C0,D0,L0,A1,B1,C1,D1,L1) asm volatile("s_waitcnt vmcnt(0)" \
  :: "v"(A0),"v"(B0),"v"(C0),"v"(D0),"v"(L0),"v"(A1),"v"(B1),"v"(C1),"v"(D1),"v"(L1) : "memory")

__device__ __forceinline__ bool tags16(u32x4 A, u32x4 B, u32x4 C, u32x4 D, u32 tag) {
  bool ok = true;
  #pragma unroll
  for (int m = 0; m < 4; m++)
    ok = ok && ((A[m] >> 16) == tag) && ((B[m] >> 16) == tag)
            && ((C[m] >> 16) == tag) && ((D[m] >> 16) == tag);
  return ok;
}
__device__ __forceinline__ void pack8(u32x4 A, u32x4 B, u32x4 C, u32x4 D, u32* pk) {
  pk[0] = (A[0] & 0xFFFFu) | (A[1] << 16); pk[1] = (A[2] & 0xFFFFu) | (A[3] << 16);
  pk[2] = (B[0] & 0xFFFFu) | (B[1] << 16); pk[3] = (B[2] & 0xFFFFu) | (B[3] << 16);
  pk[4] = (C[0] & 0xFFFFu) | (C[1] << 16); pk[5] = (C[2] & 0xFFFFu) | (C[3] << 16);
  pk[6] = (D[0] & 0xFFFFu) | (D[1] << 16); pk[7] = (D[2] & 0xFFFFu) | (D[3] << 16);
}

// Round-5 single-buffered poll — retained for the linear blocks (off critical
// path; SLP throttles their poll traffic).
template<int SLP>
__device__ __forceinline__ void pollTile(const u32* pbw, u32 tag, u32* pk) {
  while (1) {
    u32 w[16];
    u32x4 A, B2, C2, D2;
    asm volatile(
      "global_load_dwordx4 %0, %4, off sc0 sc1\n\t"
      "global_load_dwordx4 %1, %4, off offset:16 sc0 sc1\n\t"
      "global_load_dwordx4 %2, %4, off offset:32 sc0 sc1\n\t"
      "global_load_dwordx4 %3, %4, off offset:48 sc0 sc1\n\t"
      "s_waitcnt vmcnt(0)"
      : "=&v"(A), "=&v"(B2), "=&v"(C2), "=&v"(D2)
      : "v"(pbw)
      : "memory");
    #pragma unroll
    for (int m = 0; m < 4; m++) {
      w[m] = A[m]; w[4 + m] = B2[m]; w[8 + m] = C2[m]; w[12 + m] = D2[m];
    }
    bool ok = true;
    #pragma unroll
    for (int m = 0; m < 16; m++) ok = ok && ((w[m] >> 16) == tag);
    if (__all(ok)) {
      #pragma unroll
      for (int m = 0; m < 8; m++)
        pk[m] = (w[2 * m] & 0xFFFFu) | (w[2 * m + 1] << 16);
      return;
    }
    if (SLP) __builtin_amdgcn_s_sleep(SLP);
  }
}

// One-time init barrier (heavy fences OK once: flushes packed weights/x to LLC).
__device__ __forceinline__ void gbar0(u32* cnt, unsigned target) {
  __syncthreads();
  if (threadIdx.x == 0) {
    __threadfence();
    __hip_atomic_fetch_add(cnt, 1u, __ATOMIC_RELAXED, __HIP_MEMORY_SCOPE_AGENT);
    while (__hip_atomic_load(cnt, __ATOMIC_RELAXED, __HIP_MEMORY_SCOPE_AGENT) < target)
      __builtin_amdgcn_s_sleep(2);
    __threadfence();
  }
  __syncthreads();
}

__global__ void init_cnt(char* ws) {
  for (int i = threadIdx.x; i < 1024; i += 256)
    __hip_atomic_store((u32*)ws + i, 0u, __ATOMIC_RELAXED, __HIP_MEMORY_SCOPE_AGENT);
}

__global__ void __launch_bounds__(NTHR, 1) lstm_ae_kernel(
    const float* __restrict__ xin,
    const float* __restrict__ Wih1, const float* __restrict__ Whh1,
    const float* __restrict__ bih1, const float* __restrict__ bhh1,
    const float* __restrict__ Wih2, const float* __restrict__ Whh2,
    const float* __restrict__ bih2, const float* __restrict__ bhh2,
    const float* __restrict__ Wlin, const float* __restrict__ blin,
    const float* __restrict__ h10, const float* __restrict__ c10,
    const float* __restrict__ h20, const float* __restrict__ c20,
    float* __restrict__ out, char* __restrict__ ws) {
  char* ctrl = ws;
  u32* linf  = (u32*)(ctrl + CT_LIN);
  u16* xbf   = (u16*)(ws + WS_XBF);
  u16* whh1f = (u16*)(ws + WS_WHH1);
  u16* wih1f = (u16*)(ws + WS_WIH1);
  u16* wih2f = (u16*)(ws + WS_WIH2);
  u16* whh2f = (u16*)(ws + WS_WHH2);
  u16* wlinf = (u16*)(ws + WS_WLIN);
  float* b1  = (float*)(ws + WS_B1);
  float* b2  = (float*)(ws + WS_B2);
  u32* h1s   = (u32*)(ws + WS_H1T);
  u32* h2s   = (u32*)(ws + WS_H2T);

  __shared__ __align__(16) u16 Ald[16 * 512];   // staged h tile (bf16, swizzled)
  __shared__ float exch[4 * 16 * 68];           // gate preact exchange

  const int tid = blockIdx.x * NTHR + threadIdx.x;

  // ---------------- phase 0: convert/pack (proven layouts) ----------------
  for (int c = tid; c < T_ * B_ * I_ / 8; c += NTOT)
    cvt8(xin + c * 8, xbf + c * 8);
  for (int c = tid; c < (1 << 17); c += NTOT) {
    int lane = c & 63, kt = (c >> 6) & 15, g = (c >> 10) & 3, n = c >> 12;
    int row = g * 512 + n * 16 + (lane & 15);
    int k   = kt * 32 + (lane >> 4) * 8;
    cvt8(Whh1 + row * 512 + k, whh1f + c * 8);
  }
  for (int c = tid; c < (1 << 16); c += NTOT) {
    int lane = c & 63, kt = (c >> 6) & 7, g = (c >> 9) & 3, n = c >> 11;
    int row = g * 512 + n * 16 + (lane & 15);
    int k   = kt * 32 + (lane >> 4) * 8;
    cvt8(Wih1 + row * 256 + k, wih1f + c * 8);
  }
  for (int c = tid; c < (1 << 17); c += NTOT) {
    int lane = c & 63, kt = (c >> 6) & 15, g = (c >> 10) & 3, n = c >> 12;
    int row = g * 512 + n * 16 + (lane & 15);
    int k   = kt * 32 + (lane >> 4) * 8;
    cvt8(Wih2 + row * 512 + k, wih2f + c * 8);
    cvt8(Whh2 + row * 512 + k, whh2f + c * 8);
  }
  for (int c = tid; c < (1 << 14); c += NTOT) {
    int lane = c & 63, kt = (c >> 6) & 15, nt = (c >> 10) & 1, l = c >> 11;
    int row = l * 32 + nt * 16 + (lane & 15);
    int k   = kt * 32 + (lane >> 4) * 8;
    cvt8(Wlin + row * 512 + k, wlinf + c * 8);
  }
  for (int i2 = tid; i2 < 2048; i2 += NTOT) {
    b1[i2] = bih1[i2] + bhh1[i2];
    b2[i2] = bih2[i2] + bhh2[i2];
  }
  // tagged rings: slot 0 <- initial h (tag 0); other slots <- 0xFFFF (never matches)
  for (int c = tid; c < (1 << 16); c += NTOT) {       // h1: 2 slots
    int slot = c >> 15, rem = c & 32767;
    int mtd = rem >> 13, r2 = rem & 8191, row = r2 >> 9, col = r2 & 511;
    u32 v = 0xFFFF0000u;
    if (slot == 0) v = (u32)f2bf(h10[(mtd * 16 + row) * 512 + col]);
    h1s[c] = v;
  }
  for (int c = tid; c < (1 << 17); c += NTOT) {       // h2: 4 slots
    int slot = c >> 15, rem = c & 32767;
    int mtd = rem >> 13, r2 = rem & 8191, row = r2 >> 9, col = r2 & 511;
    u32 v = 0xFFFF0000u;
    if (slot == 0) v = (u32)f2bf(h20[(mtd * 16 + row) * 512 + col]);
    h2s[c] = v;
  }

  gbar0((u32*)(ctrl + CT_B0), NBLK);   // B0: packed data + ring init at LLC

  const int lane = threadIdx.x & 63;
  const int w    = threadIdx.x >> 6;         // wave 0..7
  const int l15  = lane & 15;
  const int l31  = lane & 31;
  const int qd   = lane >> 4;
  const int prow = 2 * w + (lane >> 5);      // poll/stage row of the 16-row tile
  const int swz  = (prow & 7) << 4;          // LDS XOR swizzle for stage writes
  const int pb32 = prow * 512 + l31 * 16;    // u32 index within a (slot,mt) tile

  // A-frag read: row=l15, K-chunk kt, sub-chunk qd (swizzle-consistent with stage)
  #define AFRAG(ktv) (*(const bf16x8*)((const char*)Ald + l15 * 1024 + \
                       (((ktv) * 64 + qd * 16) ^ ((l15 & 7) << 4))))
  #define STAGEA(pk) do { \
      u32x4 v0_ = {(pk)[0], (pk)[1], (pk)[2], (pk)[3]}; \
      u32x4 v1_ = {(pk)[4], (pk)[5], (pk)[6], (pk)[7]}; \
      char* ab_ = (char*)Ald + prow * 1024; \
      *(u32x4*)(ab_ + ((l31 * 32 +  0) ^ swz)) = v0_; \
      *(u32x4*)(ab_ + ((l31 * 32 + 16) ^ swz)) = v1_; \
    } while (0)

  if (blockIdx.x < NGB) {
    // ============== gate blocks: domain mt, 64 h-cols per block ==============
    const int mt = blockIdx.x >> 3;
    const int j  = blockIdx.x & 7;
    const int g  = w >> 1;                   // gate (i,f,g,o)
    const int half = w & 1;
    const int nt0 = j * 4 + half * 2;        // global 16-col tiles nt0, nt0+1

    bf16x8 Wr0[16], Wr1[16];                 // recurrent weights, register-resident
    #pragma unroll
    for (int kt = 0; kt < 16; kt++) {
      Wr0[kt] = ldg8(whh1f + ((size_t)((nt0 + 0) * 4 + g) * 16 + kt) * 512 + lane * 8);
      Wr1[kt] = ldg8(whh1f + ((size_t)((nt0 + 1) * 4 + g) * 16 + kt) * 512 + lane * 8);
    }
    const float bg0 = b1[g * 512 + (nt0 + 0) * 16 + l15];
    const float bg1 = b1[g * 512 + (nt0 + 1) * 16 + l15];

    const int hcol = j * 64 + lane;          // elementwise: rows 2w,2w+1 col=lane
    float c0v = c10[(mt * 16 + 2 * w + 0) * 512 + hcol];
    float c1v = c10[(mt * 16 + 2 * w + 1) * 512 + hcol];

    const u16* wx0 = wih1f + ((size_t)((nt0 + 0) * 4 + g) * 8) * 512 + lane * 8;
    const u16* wx1 = wih1f + ((size_t)((nt0 + 1) * 4 + g) * 8) * 512 + lane * 8;
    const int axoff = (mt * 16 + l15) * 256 + qd * 8;
    const int sobase = (2 * w) * 512 + j * 64 + lane;

    f32x4 p0, p1;                            // x-projection (+bias) for step t
    {
      p0 = f32x4{bg0, bg0, bg0, bg0};
      p1 = f32x4{bg1, bg1, bg1, bg1};
      const u16* xr = xbf + axoff;
      #pragma unroll
      for (int kt = 0; kt < 8; kt++) {
        bf16x8 ax = ldg8(xr + kt * 32);
        p0 = MFMA16(ax, ldg8(wx0 + kt * 512), p0);
        p1 = MFMA16(ax, ldg8(wx1 + kt * 512), p1);
      }
    }

    // rolling-poll state (persistent across loop iterations)
    u32x4 P0a, P0b, P0c, P0d, P1a, P1b, P1c, P1d;
    u32 P0l, P1l;

    // prologue: issue both batches for t=0 (slot 0, tag 0)
    {
      const u32* pbw = h1s + (size_t)(0 * 4 + mt) * 8192 + pb32;
      PISSF(P0a, P0b, P0c, P0d, pbw);
      PISSF(P1a, P1b, P1c, P1d, pbw);
    }

    // -------- encoder --------
    for (int t = 0; t < T_; t++) {
      u32 pk[8];
      const u32* pbw = h1s + (size_t)((t & 1) * 4 + mt) * 8192 + pb32;
      for (;;) {
        PWAITF(P0a, P0b, P0c, P0d);
        if (__all(tags16(P0a, P0b, P0c, P0d, (u32)t))) { pack8(P0a, P0b, P0c, P0d, pk); break; }
        PISSF(P0a, P0b, P0c, P0d, pbw);
        PWAITF(P1a, P1b, P1c, P1d);
        if (__all(tags16(P1a, P1b, P1c, P1d, (u32)t))) { pack8(P1a, P1b, P1c, P1d, pk); break; }
        PISSF(P1a, P1b, P1c, P1d, pbw);
      }
      STAGEA(pk);
      __syncthreads();
      f32x4 a0 = p0, a1 = p1;
      f32x4 a2 = {0.f, 0.f, 0.f, 0.f}, a3 = {0.f, 0.f, 0.f, 0.f};
      #pragma unroll
      for (int kt = 0; kt < 16; kt += 2) {
        bf16x8 af0 = AFRAG(kt), af1 = AFRAG(kt + 1);
        a0 = MFMA16(af0, Wr0[kt], a0);
        a1 = MFMA16(af0, Wr1[kt], a1);
        a2 = MFMA16(af1, Wr0[kt + 1], a2);
        a3 = MFMA16(af1, Wr1[kt + 1], a3);
      }
      a0 += a2; a1 += a3;
      #pragma unroll
      for (int r = 0; r < 4; r++) {
        exch[g * 1088 + (qd * 4 + r) * 68 + half * 32 +  0 + l15] = a0[r];
        exch[g * 1088 + (qd * 4 + r) * 68 + half * 32 + 16 + l15] = a1[r];
      }
      __syncthreads();
      PDRAIN8(P0a, P0b, P0c, P0d, P1a, P1b, P1c, P1d);   // retire leftover batch (free by now)
      {
        u32* so = h1s + (size_t)(((t + 1) & 1) * 4 + mt) * 8192 + sobase;
        #pragma unroll
        for (int rr = 0; rr < 2; rr++) {
          int rw = 2 * w + rr;
          float gi = exch[0 * 1088 + rw * 68 + lane];
          float gf = exch[1 * 1088 + rw * 68 + lane];
          float gg = exch[2 * 1088 + rw * 68 + lane];
          float go = exch[3 * 1088 + rw * 68 + lane];
          float cc = rr ? c1v : c0v;
          cc = sigm(gf) * cc + sigm(gi) * tanh_(gg);
          if (rr) c1v = cc; else c0v = cc;
          float hv = sigm(go) * tanh_(cc);
          ast32(so + rr * 512, (u32)f2bf(hv) | ((u32)(t + 1) << 16));
        }
      }
      // issue-early for t+1 (at t=T_-1 this targets the transition poll: slot 0, tag T_)
      {
        const u32* pbwn = h1s + (size_t)(((t + 1) & 1) * 4 + mt) * 8192 + pb32;
        PISSF(P0a, P0b, P0c, P0d, pbwn);
        PISSF(P1a, P1b, P1c, P1d, pbwn);
      }
      // x-projection for t+1: executes in the shadow of the in-flight poll
      if (t + 1 < T_) {
        p0 = f32x4{bg0, bg0, bg0, bg0};
        p1 = f32x4{bg1, bg1, bg1, bg1};
        const u16* xr = xbf + (size_t)(t + 1) * (B_ * I_) + axoff;
        #pragma unroll
        for (int kt = 0; kt < 8; kt++) {
          bf16x8 ax = ldg8(xr + kt * 32);
          p0 = MFMA16(ax, ldg8(wx0 + kt * 512), p0);
          p1 = MFMA16(ax, ldg8(wx1 + kt * 512), p1);
        }
      }
    }

    // -------- transition: q = b2 + h1{T} @ Wih2^T ; swap weights to LSTM2 ----
    f32x4 q0, q1;
    {
      u32 pk[8];
      const u32* pbw = h1s + (size_t)(0 * 4 + mt) * 8192 + pb32;   // T even -> slot 0
      for (;;) {
        PWAITF(P0a, P0b, P0c, P0d);
        if (__all(tags16(P0a, P0b, P0c, P0d, (u32)T_))) { pack8(P0a, P0b, P0c, P0d, pk); break; }
        PISSF(P0a, P0b, P0c, P0d, pbw);
        PWAITF(P1a, P1b, P1c, P1d);
        if (__all(tags16(P1a, P1b, P1c, P1d, (u32)T_))) { pack8(P1a, P1b, P1c, P1d, pk); break; }
        PISSF(P1a, P1b, P1c, P1d, pbw);
      }
      STAGEA(pk);
      __syncthreads();
      PDRAIN8(P0a, P0b, P0c, P0d, P1a, P1b, P1c, P1d);   // once; before q's vm loads
      const float b20 = b2[g * 512 + (nt0 + 0) * 16 + l15];
      const float b21 = b2[g * 512 + (nt0 + 1) * 16 + l15];
      q0 = f32x4{b20, b20, b20, b20};
      q1 = f32x4{b21, b21, b21, b21};
      #pragma unroll
      for (int kt = 0; kt < 16; kt++) {
        bf16x8 af = AFRAG(kt);
        q0 = MFMA16(af, ldg8(wih2f + ((size_t)((nt0 + 0) * 4 + g) * 16 + kt) * 512 + lane * 8), q0);
        q1 = MFMA16(af, ldg8(wih2f + ((size_t)((nt0 + 1) * 4 + g) * 16 + kt) * 512 + lane * 8), q1);
      }
      #pragma unroll
      for (int kt = 0; kt < 16; kt++) {
        Wr0[kt] = ldg8(whh2f + ((size_t)((nt0 + 0) * 4 + g) * 16 + kt) * 512 + lane * 8);
        Wr1[kt] = ldg8(whh2f + ((size_t)((nt0 + 1) * 4 + g) * 16 + kt) * 512 + lane * 8);
      }
      c0v = c20[(mt * 16 + 2 * w + 0) * 512 + hcol];
      c1v = c20[(mt * 16 + 2 * w + 1) * 512 + hcol];
      __syncthreads();   // Ald reads done before decoder's first stage
    }

    // decoder prologue: issue both batches for t=0 (slot 0, tag 0)
    {
      const u32* pbw = h2s + (size_t)(0 * 4 + mt) * 8192 + pb32;
      const u32* lfp = linf + mt * 2 + (lane & 1);
      PISSL(P0a, P0b, P0c, P0d, P0l, pbw, lfp);
      PISSL(P1a, P1b, P1c, P1d, P1l, pbw, lfp);
    }

    // -------- decoder --------
    for (int t = 0; t < T_; t++) {
      u32 pk[8];
      const u32* pbw = h2s + (size_t)((t & 3) * 4 + mt) * 8192 + pb32;
      const u32* lfp = linf + mt * 2 + (lane & 1);
      const int ltgt = (lane < 2) ? (t - 3) : -1;     // ring back-pressure, in-batch
      for (;;) {
        PWAITL(P0a, P0b, P0c, P0d, P0l);
        {
          bool ok = tags16(P0a, P0b, P0c, P0d, (u32)t) && ((int)P0l >= ltgt);
          if (__all(ok)) { pack8(P0a, P0b, P0c, P0d, pk); break; }
        }
        PISSL(P0a, P0b, P0c, P0d, P0l, pbw, lfp);
        PWAITL(P1a, P1b, P1c, P1d, P1l);
        {
          bool ok = tags16(P1a, P1b, P1c, P1d, (u32)t) && ((int)P1l >= ltgt);
          if (__all(ok)) { pack8(P1a, P1b, P1c, P1d, pk); break; }
        }
        PISSL(P1a, P1b, P1c, P1d, P1l, pbw, lfp);
      }
      STAGEA(pk);
      __syncthreads();
      f32x4 a0 = q0, a1 = q1;
      f32x4 a2 = {0.f, 0.f, 0.f, 0.f}, a3 = {0.f, 0.f, 0.f, 0.f};
      #pragma unroll
      for (int kt = 0; kt < 16; kt += 2) {
        bf16x8 af0 = AFRAG(kt), af1 = AFRAG(kt + 1);
        a0 = MFMA16(af0, Wr0[kt], a0);
        a1 = MFMA16(af0, Wr1[kt], a1);
        a2 = MFMA16(af1, Wr0[kt + 1], a2);
        a3 = MFMA16(af1, Wr1[kt + 1], a3);
      }
      a0 += a2; a1 += a3;
      #pragma unroll
      for (int r = 0; r < 4; r++) {
        exch[g * 1088 + (qd * 4 + r) * 68 + half * 32 +  0 + l15] = a0[r];
        exch[g * 1088 + (qd * 4 + r) * 68 + half * 32 + 16 + l15] = a1[r];
      }
      __syncthreads();
      PDRAINL(P0a, P0b, P0c, P0d, P0l, P1a, P1b, P1c, P1d, P1l);
      {
        u32* so = h2s + (size_t)(((t + 1) & 3) * 4 + mt) * 8192 + sobase;
        #pragma unroll
        for (int rr = 0; rr < 2; rr++) {
          int rw = 2 * w + rr;
          float gi = exch[0 * 1088 + rw * 68 + lane];
          float gf = exch[1 * 1088 + rw * 68 + lane];
          float gg = exch[2 * 1088 + rw * 68 + lane];
          float go = exch[3 * 1088 + rw * 68 + lane];
          float cc = rr ? c1v : c0v;
          cc = sigm(gf) * cc + sigm(gi) * tanh_(gg);
          if (rr) c1v = cc; else c0v = cc;
          float hv = sigm(go) * tanh_(cc);
          ast32(so + rr * 512, (u32)f2bf(hv) | ((u32)(t + 1) << 16));
        }
      }
      // issue-early for t+1
      if (t + 1 < T_) {
        const u32* pbwn = h2s + (size_t)(((t + 1) & 3) * 4 + mt) * 8192 + pb32;
        PISSL(P0a, P0b, P0c, P0d, P0l, pbwn, lfp);
        PISSL(P1a, P1b, P1c, P1d, P1l, pbwn, lfp);
      }
    }
  } else {
    // ============== linear blocks: (mt, q), wave = out col-tile ==============
    const int b  = blockIdx.x - NGB;
    const int mt = b >> 1, qq = b & 1;
    const int to = qq * 8 + w;               // out col-tile 0..15
    bf16x8 Wl[16];
    #pragma unroll
    for (int kt = 0; kt < 16; kt++)
      Wl[kt] = ldg8(wlinf + ((size_t)to * 16 + kt) * 512 + lane * 8);
    const float bl = blin[to * 16 + l15];
    u32* lfp = linf + mt * 2 + qq;

    // out[s] = W_lin . h2{s+1}
    for (int s = 0; s < T_; s++) {
      u32 pk[8];
      pollTile<2>(h2s + (size_t)(((s + 1) & 3) * 4 + mt) * 8192 + pb32,
                  (u32)(s + 1), pk);
      STAGEA(pk);
      __syncthreads();
      if (threadIdx.x == 0) ast32(lfp, (u32)(s + 1));   // release ring slot
      f32x4 o = {bl, bl, bl, bl};
      #pragma unroll
      for (int kt = 0; kt < 16; kt++) {
        bf16x8 af = AFRAG(kt);
        o = MFMA16(af, Wl[kt], o);
      }
      float* op = out + ((size_t)s * 64 + mt * 16 + qd * 4) * 256 + to * 16 + l15;
      #pragma unroll
      for (int r = 0; r < 4; r++) op[(size_t)r * 256] = o[r];
      __syncthreads();                       // Ald reads done before next stage
    }
  }
  #undef AFRAG
  #undef STAGEA
}

extern "C" void kernel_launch(void* const* d_in, const int* in_sizes, int n_in,
                              void* d_out, int out_size, void* d_ws, size_t ws_size,
                              hipStream_t stream) {
  (void)in_sizes; (void)n_in; (void)out_size; (void)ws_size;
  const float* xin  = (const float*)d_in[0];
  const float* Wih1 = (const float*)d_in[1];
  const float* Whh1 = (const float*)d_in[2];
  const float* bih1 = (const float*)d_in[3];
  const float* bhh1 = (const float*)d_in[4];
  const float* Wih2 = (const float*)d_in[5];
  const float* Whh2 = (const float*)d_in[6];
  const float* bih2 = (const float*)d_in[7];
  const float* bhh2 = (const float*)d_in[8];
  const float* Wlin = (const float*)d_in[9];
  const float* blin = (const float*)d_in[10];
  const float* h10  = (const float*)d_in[11];
  const float* c10  = (const float*)d_in[12];
  const float* h20  = (const float*)d_in[13];
  const float* c20  = (const float*)d_in[14];
  float* out = (float*)d_out;
  char* ws   = (char*)d_ws;

  init_cnt<<<dim3(1), dim3(256), 0, stream>>>(ws);

  void* args[] = { (void*)&xin, (void*)&Wih1, (void*)&Whh1, (void*)&bih1, (void*)&bhh1,
                   (void*)&Wih2, (void*)&Whh2, (void*)&bih2, (void*)&bhh2,
                   (void*)&Wlin, (void*)&blin, (void*)&h10, (void*)&c10,
                   (void*)&h20, (void*)&c20, (void*)&out, (void*)&ws };
  hipLaunchCooperativeKernel((void*)lstm_ae_kernel, dim3(NBLK), dim3(NTHR),
                             args, 0, stream);
}

// Round 7
// 5610.093 us; speedup vs baseline: 1.4957x; 1.4957x over previous
//
#include <hip/hip_runtime.h>
#include <hip/hip_bf16.h>

// Problem constants
#define T_ 512
#define B_ 64
#define I_ 256
#define H_ 512
#define O_ 256
#define NGB 32              // gate blocks: 4 domains x 8 blocks (64 h-cols each)
#define NLB 8               // linear blocks: 4 domains x 2 (128 out-cols each)
#define NBLK (NGB + NLB)
#define NTHR 512
#define NTOT (NBLK * NTHR)

typedef unsigned short u16;
typedef unsigned int u32;
typedef unsigned long long u64;
typedef short bf16x8 __attribute__((ext_vector_type(8)));   // 16 B = 4 VGPRs
typedef float f32x4 __attribute__((ext_vector_type(4)));
typedef u32 u32x4 __attribute__((ext_vector_type(4)));

// ---- control block (bytes 0..4095 of ws, zeroed by init_cnt) ----
#define CT_LIN   0         // u32 linf[8]: linear block (mt,q) consumed h2{linf}
#define CT_B0    64        // one-time init barrier counter

// ---- workspace layout (bytes) ----
#define WS_XBF   4096
#define WS_WHH1  (WS_XBF   + 16777216)
#define WS_WIH1  (WS_WHH1  + 2097152)
#define WS_WIH2  (WS_WIH1  + 1048576)
#define WS_WHH2  (WS_WIH2  + 2097152)
#define WS_WLIN  (WS_WHH2  + 2097152)
#define WS_B1    (WS_WLIN  + 262144)
#define WS_B2    (WS_B1    + 8192)
// tagged h rings: word = (tag<<16) | bf16(h). tile = (slot,mt): 16 rows x 512 u32
#define WS_H1T   (WS_B2    + 8192)      // 2 slots x 4 domains x 8192 u32 = 262144 B
#define WS_H2T   (WS_H1T   + 262144)    // 4 slots x 4 domains x 8192 u32 = 524288 B
#define WS_END   (WS_H2T   + 524288)

__device__ __forceinline__ u16 f2bf(float f) {
  union { float f; unsigned u; } v; v.f = f;
  unsigned r = v.u + 0x7FFFu + ((v.u >> 16) & 1u);
  return (u16)(r >> 16);
}
__device__ __forceinline__ float sigm(float x)  { return 1.0f / (1.0f + __expf(-x)); }
__device__ __forceinline__ float tanh_(float x) { return 1.0f - 2.0f / (__expf(2.0f * x) + 1.0f); }
__device__ __forceinline__ bf16x8 ldg8(const u16* p) { return *(const bf16x8*)p; }
__device__ __forceinline__ void ast32(u32* p, u32 v) {
  __hip_atomic_store(p, v, __ATOMIC_RELAXED, __HIP_MEMORY_SCOPE_AGENT);
}
#define MFMA16(a, b, c) __builtin_amdgcn_mfma_f32_16x16x32_bf16((a), (b), (c), 0, 0, 0)

// Pin a loaded value into VGPRs: the consumer then uses an asm-produced value
// the compiler cannot re-materialize by re-issuing the load. This forces the
// recurrent weights to be REGISTER-RESIDENT across all 512 steps (round-5's
// VGPR_Count=120 proved the compiler was re-loading 32 ldg8/step instead).
#define PIN(x) asm volatile("" : "+v"(x))

__device__ __forceinline__ void cvt8(const float* s, u16* dst) {
  bf16x8 v;
  #pragma unroll
  for (int jj = 0; jj < 8; jj++) v[jj] = (short)f2bf(s[jj]);
  *(bf16x8*)dst = v;
}

// ---- prefetch issue (fire-and-forget; consumed under a later vmcnt(0)) ----
#define PISSF(A,B,C,D,P) asm volatile( \
  "global_load_dwordx4 %0, %4, off sc0 sc1\n\t" \
  "global_load_dwordx4 %1, %4, off offset:16 sc0 sc1\n\t" \
  "global_load_dwordx4 %2, %4, off offset:32 sc0 sc1\n\t" \
  "global_load_dwordx4 %3, %4, off offset:48 sc0 sc1" \
  : "=&v"(A), "=&v"(B), "=&v"(C), "=&v"(D) : "v"(P) : "memory")

#define PISSL(A,B,C,D,L,P,Q) asm volatile( \
  "global_load_dwordx4 %0, %5, off sc0 sc1\n\t" \
  "global_load_dwordx4 %1, %5, off offset:16 sc0 sc1\n\t" \
  "global_load_dwordx4 %2, %5, off offset:32 sc0 sc1\n\t" \
  "global_load_dwordx4 %3, %5, off offset:48 sc0 sc1\n\t" \
  "global_load_dword   %4, %6, off sc0 sc1" \
  : "=&v"(A), "=&v"(B), "=&v"(C), "=&v"(D), "=&v"(L) : "v"(P), "v"(Q) : "memory")

// Full-drain wait (SAFE vs round-6: vmcnt(0) regardless of compiler interleave)
#define PWAIT0(A,B,C,D) asm volatile("s_waitcnt vmcnt(0)" \
  : "+v"(A), "+v"(B), "+v"(C), "+v"(D) :: "memory")
#define PWAIT0L(A,B,C,D,L) asm volatile("s_waitcnt vmcnt(0)" \
  : "+v"(A), "+v"(B), "+v"(C), "+v"(D), "+v"(L) :: "memory")

__device__ __forceinline__ bool tags16(u32x4 A, u32x4 B, u32x4 C, u32x4 D, u32 tag) {
  bool ok = true;
  #pragma unroll
  for (int m = 0; m < 4; m++)
    ok = ok && ((A[m] >> 16) == tag) && ((B[m] >> 16) == tag)
            && ((C[m] >> 16) == tag) && ((D[m] >> 16) == tag);
  return ok;
}
__device__ __forceinline__ void pack8(u32x4 A, u32x4 B, u32x4 C, u32x4 D, u32* pk) {
  pk[0] = (A[0] & 0xFFFFu) | (A[1] << 16); pk[1] = (A[2] & 0xFFFFu) | (A[3] << 16);
  pk[2] = (B[0] & 0xFFFFu) | (B[1] << 16); pk[3] = (B[2] & 0xFFFFu) | (B[3] << 16);
  pk[4] = (C[0] & 0xFFFFu) | (C[1] << 16); pk[5] = (C[2] & 0xFFFFu) | (C[3] << 16);
  pk[6] = (D[0] & 0xFFFFu) | (D[1] << 16); pk[7] = (D[2] & 0xFFFFu) | (D[3] << 16);
}

// Round-5 proven poll (batched loads, one vmcnt(0) per iteration).
template<bool LINCHK, int SLP>
__device__ __forceinline__ void pollTile(const u32* pbw, u32 tag,
                                         const u32* lfp, int ltgt, u32* pk) {
  while (1) {
    u32 w[16];
    bool ok = true;
    u32x4 A, B2, C2, D2;
    if (LINCHK) {
      u32 lv;
      asm volatile(
        "global_load_dwordx4 %0, %5, off sc0 sc1\n\t"
        "global_load_dwordx4 %1, %5, off offset:16 sc0 sc1\n\t"
        "global_load_dwordx4 %2, %5, off offset:32 sc0 sc1\n\t"
        "global_load_dwordx4 %3, %5, off offset:48 sc0 sc1\n\t"
        "global_load_dword   %4, %6, off sc0 sc1\n\t"
        "s_waitcnt vmcnt(0)"
        : "=&v"(A), "=&v"(B2), "=&v"(C2), "=&v"(D2), "=&v"(lv)
        : "v"(pbw), "v"(lfp)
        : "memory");
      ok = (int)lv >= ltgt;
    } else {
      asm volatile(
        "global_load_dwordx4 %0, %4, off sc0 sc1\n\t"
        "global_load_dwordx4 %1, %4, off offset:16 sc0 sc1\n\t"
        "global_load_dwordx4 %2, %4, off offset:32 sc0 sc1\n\t"
        "global_load_dwordx4 %3, %4, off offset:48 sc0 sc1\n\t"
        "s_waitcnt vmcnt(0)"
        : "=&v"(A), "=&v"(B2), "=&v"(C2), "=&v"(D2)
        : "v"(pbw)
        : "memory");
    }
    #pragma unroll
    for (int m = 0; m < 4; m++) {
      w[m] = A[m]; w[4 + m] = B2[m]; w[8 + m] = C2[m]; w[12 + m] = D2[m];
    }
    #pragma unroll
    for (int m = 0; m < 16; m++) ok = ok && ((w[m] >> 16) == tag);
    if (__all(ok)) {
      #pragma unroll
      for (int m = 0; m < 8; m++)
        pk[m] = (w[2 * m] & 0xFFFFu) | (w[2 * m + 1] << 16);
      return;
    }
    if (SLP) __builtin_amdgcn_s_sleep(SLP);
  }
}

// One-time init barrier (heavy fences OK once: flushes packed weights/x to LLC).
__device__ __forceinline__ void gbar0(u32* cnt, unsigned target) {
  __syncthreads();
  if (threadIdx.x == 0) {
    __threadfence();
    __hip_atomic_fetch_add(cnt, 1u, __ATOMIC_RELAXED, __HIP_MEMORY_SCOPE_AGENT);
    while (__hip_atomic_load(cnt, __ATOMIC_RELAXED, __HIP_MEMORY_SCOPE_AGENT) < target)
      __builtin_amdgcn_s_sleep(2);
    __threadfence();
  }
  __syncthreads();
}

__global__ void init_cnt(char* ws) {
  for (int i = threadIdx.x; i < 1024; i += 256)
    __hip_atomic_store((u32*)ws + i, 0u, __ATOMIC_RELAXED, __HIP_MEMORY_SCOPE_AGENT);
}

__global__ void __launch_bounds__(NTHR, 1) lstm_ae_kernel(
    const float* __restrict__ xin,
    const float* __restrict__ Wih1, const float* __restrict__ Whh1,
    const float* __restrict__ bih1, const float* __restrict__ bhh1,
    const float* __restrict__ Wih2, const float* __restrict__ Whh2,
    const float* __restrict__ bih2, const float* __restrict__ bhh2,
    const float* __restrict__ Wlin, const float* __restrict__ blin,
    const float* __restrict__ h10, const float* __restrict__ c10,
    const float* __restrict__ h20, const float* __restrict__ c20,
    float* __restrict__ out, char* __restrict__ ws) {
  char* ctrl = ws;
  u32* linf  = (u32*)(ctrl + CT_LIN);
  u16* xbf   = (u16*)(ws + WS_XBF);
  u16* whh1f = (u16*)(ws + WS_WHH1);
  u16* wih1f = (u16*)(ws + WS_WIH1);
  u16* wih2f = (u16*)(ws + WS_WIH2);
  u16* whh2f = (u16*)(ws + WS_WHH2);
  u16* wlinf = (u16*)(ws + WS_WLIN);
  float* b1  = (float*)(ws + WS_B1);
  float* b2  = (float*)(ws + WS_B2);
  u32* h1s   = (u32*)(ws + WS_H1T);
  u32* h2s   = (u32*)(ws + WS_H2T);

  __shared__ __align__(16) u16 Ald[16 * 512];   // staged h tile (bf16, swizzled)
  __shared__ float exch[4 * 16 * 68];           // gate preact exchange

  const int tid = blockIdx.x * NTHR + threadIdx.x;

  // ---------------- phase 0: convert/pack (proven layouts) ----------------
  for (int c = tid; c < T_ * B_ * I_ / 8; c += NTOT)
    cvt8(xin + c * 8, xbf + c * 8);
  for (int c = tid; c < (1 << 17); c += NTOT) {
    int lane = c & 63, kt = (c >> 6) & 15, g = (c >> 10) & 3, n = c >> 12;
    int row = g * 512 + n * 16 + (lane & 15);
    int k   = kt * 32 + (lane >> 4) * 8;
    cvt8(Whh1 + row * 512 + k, whh1f + c * 8);
  }
  for (int c = tid; c < (1 << 16); c += NTOT) {
    int lane = c & 63, kt = (c >> 6) & 7, g = (c >> 9) & 3, n = c >> 11;
    int row = g * 512 + n * 16 + (lane & 15);
    int k   = kt * 32 + (lane >> 4) * 8;
    cvt8(Wih1 + row * 256 + k, wih1f + c * 8);
  }
  for (int c = tid; c < (1 << 17); c += NTOT) {
    int lane = c & 63, kt = (c >> 6) & 15, g = (c >> 10) & 3, n = c >> 12;
    int row = g * 512 + n * 16 + (lane & 15);
    int k   = kt * 32 + (lane >> 4) * 8;
    cvt8(Wih2 + row * 512 + k, wih2f + c * 8);
    cvt8(Whh2 + row * 512 + k, whh2f + c * 8);
  }
  for (int c = tid; c < (1 << 14); c += NTOT) {
    int lane = c & 63, kt = (c >> 6) & 15, nt = (c >> 10) & 1, l = c >> 11;
    int row = l * 32 + nt * 16 + (lane & 15);
    int k   = kt * 32 + (lane >> 4) * 8;
    cvt8(Wlin + row * 512 + k, wlinf + c * 8);
  }
  for (int i2 = tid; i2 < 2048; i2 += NTOT) {
    b1[i2] = bih1[i2] + bhh1[i2];
    b2[i2] = bih2[i2] + bhh2[i2];
  }
  // tagged rings: slot 0 <- initial h (tag 0); other slots <- 0xFFFF (never matches)
  for (int c = tid; c < (1 << 16); c += NTOT) {       // h1: 2 slots
    int slot = c >> 15, rem = c & 32767;
    int mtd = rem >> 13, r2 = rem & 8191, row = r2 >> 9, col = r2 & 511;
    u32 v = 0xFFFF0000u;
    if (slot == 0) v = (u32)f2bf(h10[(mtd * 16 + row) * 512 + col]);
    h1s[c] = v;
  }
  for (int c = tid; c < (1 << 17); c += NTOT) {       // h2: 4 slots
    int slot = c >> 15, rem = c & 32767;
    int mtd = rem >> 13, r2 = rem & 8191, row = r2 >> 9, col = r2 & 511;
    u32 v = 0xFFFF0000u;
    if (slot == 0) v = (u32)f2bf(h20[(mtd * 16 + row) * 512 + col]);
    h2s[c] = v;
  }

  gbar0((u32*)(ctrl + CT_B0), NBLK);   // B0: packed data + ring init at LLC

  const int lane = threadIdx.x & 63;
  const int w    = threadIdx.x >> 6;         // wave 0..7
  const int l15  = lane & 15;
  const int l31  = lane & 31;
  const int qd   = lane >> 4;
  const int prow = 2 * w + (lane >> 5);      // poll/stage row of the 16-row tile
  const int swz  = (prow & 7) << 4;          // LDS XOR swizzle for stage writes
  const int pb32 = prow * 512 + l31 * 16;    // u32 index within a (slot,mt) tile

  // A-frag read: row=l15, K-chunk kt, sub-chunk qd (swizzle-consistent with stage)
  #define AFRAG(ktv) (*(const bf16x8*)((const char*)Ald + l15 * 1024 + \
                       (((ktv) * 64 + qd * 16) ^ ((l15 & 7) << 4))))
  #define STAGEA(pk) do { \
      u32x4 v0_ = {(pk)[0], (pk)[1], (pk)[2], (pk)[3]}; \
      u32x4 v1_ = {(pk)[4], (pk)[5], (pk)[6], (pk)[7]}; \
      char* ab_ = (char*)Ald + prow * 1024; \
      *(u32x4*)(ab_ + ((l31 * 32 +  0) ^ swz)) = v0_; \
      *(u32x4*)(ab_ + ((l31 * 32 + 16) ^ swz)) = v1_; \
    } while (0)

  if (blockIdx.x < NGB) {
    // ============== gate blocks: domain mt, 64 h-cols per block ==============
    const int mt = blockIdx.x >> 3;
    const int j  = blockIdx.x & 7;
    const int g  = w >> 1;                   // gate (i,f,g,o)
    const int half = w & 1;
    const int nt0 = j * 4 + half * 2;        // global 16-col tiles nt0, nt0+1

    bf16x8 Wr0[16], Wr1[16];                 // recurrent weights, REGISTER-pinned
    #pragma unroll
    for (int kt = 0; kt < 16; kt++) {
      Wr0[kt] = ldg8(whh1f + ((size_t)((nt0 + 0) * 4 + g) * 16 + kt) * 512 + lane * 8);
      Wr1[kt] = ldg8(whh1f + ((size_t)((nt0 + 1) * 4 + g) * 16 + kt) * 512 + lane * 8);
    }
    #pragma unroll
    for (int kt = 0; kt < 16; kt++) { PIN(Wr0[kt]); PIN(Wr1[kt]); }

    const float bg0 = b1[g * 512 + (nt0 + 0) * 16 + l15];
    const float bg1 = b1[g * 512 + (nt0 + 1) * 16 + l15];

    const int hcol = j * 64 + lane;          // elementwise: rows 2w,2w+1 col=lane
    float c0v = c10[(mt * 16 + 2 * w + 0) * 512 + hcol];
    float c1v = c10[(mt * 16 + 2 * w + 1) * 512 + hcol];

    const u16* wx0 = wih1f + ((size_t)((nt0 + 0) * 4 + g) * 8) * 512 + lane * 8;
    const u16* wx1 = wih1f + ((size_t)((nt0 + 1) * 4 + g) * 8) * 512 + lane * 8;
    const int axoff = (mt * 16 + l15) * 256 + qd * 8;
    const int sobase = (2 * w) * 512 + j * 64 + lane;

    f32x4 p0, p1;                            // x-projection (+bias) for step t
    {
      p0 = f32x4{bg0, bg0, bg0, bg0};
      p1 = f32x4{bg1, bg1, bg1, bg1};
      const u16* xr = xbf + axoff;
      #pragma unroll
      for (int kt = 0; kt < 8; kt++) {
        bf16x8 ax = ldg8(xr + kt * 32);
        p0 = MFMA16(ax, ldg8(wx0 + kt * 512), p0);
        p1 = MFMA16(ax, ldg8(wx1 + kt * 512), p1);
      }
    }

    // prefetch state for the poll (consumed under vmcnt(0) — interleave-safe)
    u32x4 Fa, Fb, Fc, Fd;
    u32 Fl;
    PISSF(Fa, Fb, Fc, Fd, h1s + (size_t)(0 * 4 + mt) * 8192 + pb32);

    // -------- encoder --------
    for (int t = 0; t < T_; t++) {
      u32 pk[8];
      const u32* pbw = h1s + (size_t)((t & 1) * 4 + mt) * 8192 + pb32;
      PWAIT0(Fa, Fb, Fc, Fd);
      if (__all(tags16(Fa, Fb, Fc, Fd, (u32)t)))
        pack8(Fa, Fb, Fc, Fd, pk);
      else
        pollTile<false, 0>(pbw, (u32)t, linf, 0, pk);
      STAGEA(pk);
      __syncthreads();
      f32x4 a0 = p0, a1 = p1;
      f32x4 a2 = {0.f, 0.f, 0.f, 0.f}, a3 = {0.f, 0.f, 0.f, 0.f};
      #pragma unroll
      for (int kt = 0; kt < 16; kt += 2) {
        bf16x8 af0 = AFRAG(kt), af1 = AFRAG(kt + 1);
        a0 = MFMA16(af0, Wr0[kt], a0);
        a1 = MFMA16(af0, Wr1[kt], a1);
        a2 = MFMA16(af1, Wr0[kt + 1], a2);
        a3 = MFMA16(af1, Wr1[kt + 1], a3);
      }
      a0 += a2; a1 += a3;
      #pragma unroll
      for (int r = 0; r < 4; r++) {
        exch[g * 1088 + (qd * 4 + r) * 68 + half * 32 +  0 + l15] = a0[r];
        exch[g * 1088 + (qd * 4 + r) * 68 + half * 32 + 16 + l15] = a1[r];
      }
      __syncthreads();
      {
        u32* so = h1s + (size_t)(((t + 1) & 1) * 4 + mt) * 8192 + sobase;
        #pragma unroll
        for (int rr = 0; rr < 2; rr++) {
          int rw = 2 * w + rr;
          float gi = exch[0 * 1088 + rw * 68 + lane];
          float gf = exch[1 * 1088 + rw * 68 + lane];
          float gg = exch[2 * 1088 + rw * 68 + lane];
          float go = exch[3 * 1088 + rw * 68 + lane];
          float cc = rr ? c1v : c0v;
          cc = sigm(gf) * cc + sigm(gi) * tanh_(gg);
          if (rr) c1v = cc; else c0v = cc;
          float hv = sigm(go) * tanh_(cc);
          ast32(so + rr * 512, (u32)f2bf(hv) | ((u32)(t + 1) << 16));
        }
      }
      // prefetch poll batch for t+1 (AFTER own stores so own tags can match);
      // its LLC round trip hides under the x-projection below.
      PISSF(Fa, Fb, Fc, Fd, h1s + (size_t)(((t + 1) & 1) * 4 + mt) * 8192 + pb32);
      // x-projection for t+1: executes in the shadow of the in-flight prefetch
      if (t + 1 < T_) {
        p0 = f32x4{bg0, bg0, bg0, bg0};
        p1 = f32x4{bg1, bg1, bg1, bg1};
        const u16* xr = xbf + (size_t)(t + 1) * (B_ * I_) + axoff;
        #pragma unroll
        for (int kt = 0; kt < 8; kt++) {
          bf16x8 ax = ldg8(xr + kt * 32);
          p0 = MFMA16(ax, ldg8(wx0 + kt * 512), p0);
          p1 = MFMA16(ax, ldg8(wx1 + kt * 512), p1);
        }
      }
    }

    // -------- transition: q = b2 + h1{T} @ Wih2^T ; swap weights to LSTM2 ----
    f32x4 q0, q1;
    {
      u32 pk[8];
      const u32* pbw = h1s + (size_t)(0 * 4 + mt) * 8192 + pb32;   // T even -> slot 0
      PWAIT0(Fa, Fb, Fc, Fd);
      if (__all(tags16(Fa, Fb, Fc, Fd, (u32)T_)))
        pack8(Fa, Fb, Fc, Fd, pk);
      else
        pollTile<false, 0>(pbw, (u32)T_, linf, 0, pk);
      STAGEA(pk);
      __syncthreads();
      const float b20 = b2[g * 512 + (nt0 + 0) * 16 + l15];
      const float b21 = b2[g * 512 + (nt0 + 1) * 16 + l15];
      q0 = f32x4{b20, b20, b20, b20};
      q1 = f32x4{b21, b21, b21, b21};
      #pragma unroll
      for (int kt = 0; kt < 16; kt++) {
        bf16x8 af = AFRAG(kt);
        q0 = MFMA16(af, ldg8(wih2f + ((size_t)((nt0 + 0) * 4 + g) * 16 + kt) * 512 + lane * 8), q0);
        q1 = MFMA16(af, ldg8(wih2f + ((size_t)((nt0 + 1) * 4 + g) * 16 + kt) * 512 + lane * 8), q1);
      }
      #pragma unroll
      for (int kt = 0; kt < 16; kt++) {
        Wr0[kt] = ldg8(whh2f + ((size_t)((nt0 + 0) * 4 + g) * 16 + kt) * 512 + lane * 8);
        Wr1[kt] = ldg8(whh2f + ((size_t)((nt0 + 1) * 4 + g) * 16 + kt) * 512 + lane * 8);
      }
      #pragma unroll
      for (int kt = 0; kt < 16; kt++) { PIN(Wr0[kt]); PIN(Wr1[kt]); }
      c0v = c20[(mt * 16 + 2 * w + 0) * 512 + hcol];
      c1v = c20[(mt * 16 + 2 * w + 1) * 512 + hcol];
      __syncthreads();   // Ald reads done before decoder's first stage
    }

    const u32* lfp = linf + mt * 2 + (lane & 1);
    // decoder prologue prefetch (slot 0, tag 0)
    PISSL(Fa, Fb, Fc, Fd, Fl, h2s + (size_t)(0 * 4 + mt) * 8192 + pb32, lfp);

    // -------- decoder --------
    for (int t = 0; t < T_; t++) {
      u32 pk[8];
      const u32* pbw = h2s + (size_t)((t & 3) * 4 + mt) * 8192 + pb32;
      const int ltgt = (lane < 2) ? (t - 3) : -1;     // ring back-pressure, in-batch
      PWAIT0L(Fa, Fb, Fc, Fd, Fl);
      {
        bool ok = tags16(Fa, Fb, Fc, Fd, (u32)t) && ((int)Fl >= ltgt);
        if (__all(ok))
          pack8(Fa, Fb, Fc, Fd, pk);
        else
          pollTile<true, 0>(pbw, (u32)t, lfp, ltgt, pk);
      }
      STAGEA(pk);
      __syncthreads();
      f32x4 a0 = q0, a1 = q1;
      f32x4 a2 = {0.f, 0.f, 0.f, 0.f}, a3 = {0.f, 0.f, 0.f, 0.f};
      #pragma unroll
      for (int kt = 0; kt < 16; kt += 2) {
        bf16x8 af0 = AFRAG(kt), af1 = AFRAG(kt + 1);
        a0 = MFMA16(af0, Wr0[kt], a0);
        a1 = MFMA16(af0, Wr1[kt], a1);
        a2 = MFMA16(af1, Wr0[kt + 1], a2);
        a3 = MFMA16(af1, Wr1[kt + 1], a3);
      }
      a0 += a2; a1 += a3;
      #pragma unroll
      for (int r = 0; r < 4; r++) {
        exch[g * 1088 + (qd * 4 + r) * 68 + half * 32 +  0 + l15] = a0[r];
        exch[g * 1088 + (qd * 4 + r) * 68 + half * 32 + 16 + l15] = a1[r];
      }
      __syncthreads();
      {
        u32* so = h2s + (size_t)(((t + 1) & 3) * 4 + mt) * 8192 + sobase;
        #pragma unroll
        for (int rr = 0; rr < 2; rr++) {
          int rw = 2 * w + rr;
          float gi = exch[0 * 1088 + rw * 68 + lane];
          float gf = exch[1 * 1088 + rw * 68 + lane];
          float gg = exch[2 * 1088 + rw * 68 + lane];
          float go = exch[3 * 1088 + rw * 68 + lane];
          float cc = rr ? c1v : c0v;
          cc = sigm(gf) * cc + sigm(gi) * tanh_(gg);
          if (rr) c1v = cc; else c0v = cc;
          float hv = sigm(go) * tanh_(cc);
          ast32(so + rr * 512, (u32)f2bf(hv) | ((u32)(t + 1) << 16));
        }
      }
      // prefetch for t+1 (after own stores)
      if (t + 1 < T_)
        PISSL(Fa, Fb, Fc, Fd, Fl,
              h2s + (size_t)(((t + 1) & 3) * 4 + mt) * 8192 + pb32, lfp);
    }
  } else {
    // ============== linear blocks: (mt, q), wave = out col-tile ==============
    const int b  = blockIdx.x - NGB;
    const int mt = b >> 1, qq = b & 1;
    const int to = qq * 8 + w;               // out col-tile 0..15
    bf16x8 Wl[16];
    #pragma unroll
    for (int kt = 0; kt < 16; kt++)
      Wl[kt] = ldg8(wlinf + ((size_t)to * 16 + kt) * 512 + lane * 8);
    #pragma unroll
    for (int kt = 0; kt < 16; kt++) PIN(Wl[kt]);
    const float bl = blin[to * 16 + l15];
    u32* lfp = linf + mt * 2 + qq;

    // out[s] = W_lin . h2{s+1}
    for (int s = 0; s < T_; s++) {
      u32 pk[8];
      pollTile<false, 2>(h2s + (size_t)(((s + 1) & 3) * 4 + mt) * 8192 + pb32,
                         (u32)(s + 1), linf, 0, pk);
      STAGEA(pk);
      __syncthreads();
      if (threadIdx.x == 0) ast32(lfp, (u32)(s + 1));   // release ring slot
      f32x4 o = {bl, bl, bl, bl};
      #pragma unroll
      for (int kt = 0; kt < 16; kt++) {
        bf16x8 af = AFRAG(kt);
        o = MFMA16(af, Wl[kt], o);
      }
      float* op = out + ((size_t)s * 64 + mt * 16 + qd * 4) * 256 + to * 16 + l15;
      #pragma unroll
      for (int r = 0; r < 4; r++) op[(size_t)r * 256] = o[r];
      __syncthreads();                       // Ald reads done before next stage
    }
  }
  #undef AFRAG
  #undef STAGEA
}

extern "C" void kernel_launch(void* const* d_in, const int* in_sizes, int n_in,
                              void* d_out, int out_size, void* d_ws, size_t ws_size,
                              hipStream_t stream) {
  (void)in_sizes; (void)n_in; (void)out_size; (void)ws_size;
  const float* xin  = (const float*)d_in[0];
  const float* Wih1 = (const float*)d_in[1];
  const float* Whh1 = (const float*)d_in[2];
  const float* bih1 = (const float*)d_in[3];
  const float* bhh1 = (const float*)d_in[4];
  const float* Wih2 = (const float*)d_in[5];
  const float* Whh2 = (const float*)d_in[6];
  const float* bih2 = (const float*)d_in[7];
  const float* bhh2 = (const float*)d_in[8];
  const float* Wlin = (const float*)d_in[9];
  const float* blin = (const float*)d_in[10];
  const float* h10  = (const float*)d_in[11];
  const float* c10  = (const float*)d_in[12];
  const float* h20  = (const float*)d_in[13];
  const float* c20  = (const float*)d_in[14];
  float* out = (float*)d_out;
  char* ws   = (char*)d_ws;

  init_cnt<<<dim3(1), dim3(256), 0, stream>>>(ws);

  void* args[] = { (void*)&xin, (void*)&Wih1, (void*)&Whh1, (void*)&bih1, (void*)&bhh1,
                   (void*)&Wih2, (void*)&Whh2, (void*)&bih2, (void*)&bhh2,
                   (void*)&Wlin, (void*)&blin, (void*)&h10, (void*)&c10,
                   (void*)&h20, (void*)&c20, (void*)&out, (void*)&ws };
  hipLaunchCooperativeKernel((void*)lstm_ae_kernel, dim3(NBLK), dim3(NTHR),
                             args, 0, stream);
}

// Round 8
// 4953.211 us; speedup vs baseline: 1.6940x; 1.1326x over previous
//
#include <hip/hip_runtime.h>
#include <hip/hip_bf16.h>

// Problem constants
#define T_ 512
#define B_ 64
#define I_ 256
#define H_ 512
#define O_ 256
#define NGB 32              // gate blocks: 4 domains x 8 blocks (64 h-cols each)
#define NLB 8               // linear blocks: 4 domains x 2 (128 out-cols each)
#define NBLK (NGB + NLB)
#define NTHR 512
#define NTOT (NBLK * NTHR)

typedef unsigned short u16;
typedef unsigned int u32;
typedef unsigned long long u64;
typedef short bf16x8 __attribute__((ext_vector_type(8)));   // 16 B = 4 VGPRs
typedef float f32x4 __attribute__((ext_vector_type(4)));
typedef u32 u32x4 __attribute__((ext_vector_type(4)));

// ---- control block (bytes 0..4095 of ws, zeroed by init_cnt) ----
#define CT_LIN   0         // u32 linf[8]: linear block (mt,q) consumed h2{linf}
#define CT_B0    64        // one-time init barrier counter

// ---- workspace layout (bytes) ----
#define WS_XBF   4096
#define WS_WHH1  (WS_XBF   + 16777216)
#define WS_WIH1  (WS_WHH1  + 2097152)
#define WS_WIH2  (WS_WIH1  + 1048576)
#define WS_WHH2  (WS_WIH2  + 2097152)
#define WS_WLIN  (WS_WHH2  + 2097152)
#define WS_B1    (WS_WLIN  + 262144)
#define WS_B2    (WS_B1    + 8192)
// tagged h rings: word = (tag<<16) | bf16(h). tile = (slot,mt): 16 rows x 512 u32
#define WS_H1T   (WS_B2    + 8192)      // 2 slots x 4 domains x 8192 u32 = 262144 B
#define WS_H2T   (WS_H1T   + 262144)    // 4 slots x 4 domains x 8192 u32 = 524288 B
#define WS_END   (WS_H2T   + 524288)

__device__ __forceinline__ u16 f2bf(float f) {
  union { float f; unsigned u; } v; v.f = f;
  unsigned r = v.u + 0x7FFFu + ((v.u >> 16) & 1u);
  return (u16)(r >> 16);
}
__device__ __forceinline__ float sigm(float x)  { return 1.0f / (1.0f + __expf(-x)); }
__device__ __forceinline__ float tanh_(float x) { return 1.0f - 2.0f / (__expf(2.0f * x) + 1.0f); }
__device__ __forceinline__ bf16x8 ldg8(const u16* p) { return *(const bf16x8*)p; }
__device__ __forceinline__ void ast32(u32* p, u32 v) {
  __hip_atomic_store(p, v, __ATOMIC_RELAXED, __HIP_MEMORY_SCOPE_AGENT);
}
#define MFMA16(a, b, c) __builtin_amdgcn_mfma_f32_16x16x32_bf16((a), (b), (c), 0, 0, 0)

__device__ __forceinline__ void cvt8(const float* s, u16* dst) {
  bf16x8 v;
  #pragma unroll
  for (int jj = 0; jj < 8; jj++) v[jj] = (short)f2bf(s[jj]);
  *(bf16x8*)dst = v;
}

// Poll one 2-row slice (16 u32/lane = 64B) of a tagged tile until every word's
// tag==tag; payloads (already in regs) are packed into pk[8].
// SCOPE FIX vs round-5: round-5 polled with "sc0 sc1" = SYSTEM scope -> every
// iteration was an HBM round trip (FETCH_SIZE 622MB = poll traffic). The
// h-stores are agent atomics = DEVICE scope (sc1) committing at the LLC, so
// polling at device scope ("sc1" only) reads the same coherence point with an
// LLC-latency round trip instead of HBM. Sticky timeout (4096 iters) falls
// back to the proven system-scope poll — hang-proof if sc1 loads were ever
// served stale.
template<bool LINCHK, int SLP>
__device__ __forceinline__ void pollTile(const u32* pbw, u32 tag,
                                         const u32* lfp, int ltgt, u32* pk,
                                         bool& devok) {
  if (devok) {
    int it = 0;
    while (1) {
      u32 w[16];
      bool ok = true;
      u32x4 A, B2, C2, D2;
      if (LINCHK) {
        u32 lv;
        asm volatile(
          "global_load_dwordx4 %0, %5, off sc1\n\t"
          "global_load_dwordx4 %1, %5, off offset:16 sc1\n\t"
          "global_load_dwordx4 %2, %5, off offset:32 sc1\n\t"
          "global_load_dwordx4 %3, %5, off offset:48 sc1\n\t"
          "global_load_dword   %4, %6, off sc1\n\t"
          "s_waitcnt vmcnt(0)"
          : "=&v"(A), "=&v"(B2), "=&v"(C2), "=&v"(D2), "=&v"(lv)
          : "v"(pbw), "v"(lfp)
          : "memory");
        ok = (int)lv >= ltgt;
      } else {
        asm volatile(
          "global_load_dwordx4 %0, %4, off sc1\n\t"
          "global_load_dwordx4 %1, %4, off offset:16 sc1\n\t"
          "global_load_dwordx4 %2, %4, off offset:32 sc1\n\t"
          "global_load_dwordx4 %3, %4, off offset:48 sc1\n\t"
          "s_waitcnt vmcnt(0)"
          : "=&v"(A), "=&v"(B2), "=&v"(C2), "=&v"(D2)
          : "v"(pbw)
          : "memory");
      }
      #pragma unroll
      for (int m = 0; m < 4; m++) {
        w[m] = A[m]; w[4 + m] = B2[m]; w[8 + m] = C2[m]; w[12 + m] = D2[m];
      }
      #pragma unroll
      for (int m = 0; m < 16; m++) ok = ok && ((w[m] >> 16) == tag);
      if (__all(ok)) {
        #pragma unroll
        for (int m = 0; m < 8; m++)
          pk[m] = (w[2 * m] & 0xFFFFu) | (w[2 * m + 1] << 16);
        return;
      }
      if (++it >= 4096) { devok = false; break; }   // sticky fallback
      if (SLP) __builtin_amdgcn_s_sleep(SLP);
    }
  }
  // fallback: system-scope poll (round-5 proven)
  while (1) {
    u32 w[16];
    bool ok = true;
    u32x4 A, B2, C2, D2;
    if (LINCHK) {
      u32 lv;
      asm volatile(
        "global_load_dwordx4 %0, %5, off sc0 sc1\n\t"
        "global_load_dwordx4 %1, %5, off offset:16 sc0 sc1\n\t"
        "global_load_dwordx4 %2, %5, off offset:32 sc0 sc1\n\t"
        "global_load_dwordx4 %3, %5, off offset:48 sc0 sc1\n\t"
        "global_load_dword   %4, %6, off sc0 sc1\n\t"
        "s_waitcnt vmcnt(0)"
        : "=&v"(A), "=&v"(B2), "=&v"(C2), "=&v"(D2), "=&v"(lv)
        : "v"(pbw), "v"(lfp)
        : "memory");
      ok = (int)lv >= ltgt;
    } else {
      asm volatile(
        "global_load_dwordx4 %0, %4, off sc0 sc1\n\t"
        "global_load_dwordx4 %1, %4, off offset:16 sc0 sc1\n\t"
        "global_load_dwordx4 %2, %4, off offset:32 sc0 sc1\n\t"
        "global_load_dwordx4 %3, %4, off offset:48 sc0 sc1\n\t"
        "s_waitcnt vmcnt(0)"
        : "=&v"(A), "=&v"(B2), "=&v"(C2), "=&v"(D2)
        : "v"(pbw)
        : "memory");
    }
    #pragma unroll
    for (int m = 0; m < 4; m++) {
      w[m] = A[m]; w[4 + m] = B2[m]; w[8 + m] = C2[m]; w[12 + m] = D2[m];
    }
    #pragma unroll
    for (int m = 0; m < 16; m++) ok = ok && ((w[m] >> 16) == tag);
    if (__all(ok)) {
      #pragma unroll
      for (int m = 0; m < 8; m++)
        pk[m] = (w[2 * m] & 0xFFFFu) | (w[2 * m + 1] << 16);
      return;
    }
    if (SLP) __builtin_amdgcn_s_sleep(SLP);
  }
}

// One-time init barrier (heavy fences OK once: flushes packed weights/x to LLC).
__device__ __forceinline__ void gbar0(u32* cnt, unsigned target) {
  __syncthreads();
  if (threadIdx.x == 0) {
    __threadfence();
    __hip_atomic_fetch_add(cnt, 1u, __ATOMIC_RELAXED, __HIP_MEMORY_SCOPE_AGENT);
    while (__hip_atomic_load(cnt, __ATOMIC_RELAXED, __HIP_MEMORY_SCOPE_AGENT) < target)
      __builtin_amdgcn_s_sleep(2);
    __threadfence();
  }
  __syncthreads();
}

__global__ void init_cnt(char* ws) {
  for (int i = threadIdx.x; i < 1024; i += 256)
    __hip_atomic_store((u32*)ws + i, 0u, __ATOMIC_RELAXED, __HIP_MEMORY_SCOPE_AGENT);
}

__global__ void __launch_bounds__(NTHR, 1) lstm_ae_kernel(
    const float* __restrict__ xin,
    const float* __restrict__ Wih1, const float* __restrict__ Whh1,
    const float* __restrict__ bih1, const float* __restrict__ bhh1,
    const float* __restrict__ Wih2, const float* __restrict__ Whh2,
    const float* __restrict__ bih2, const float* __restrict__ bhh2,
    const float* __restrict__ Wlin, const float* __restrict__ blin,
    const float* __restrict__ h10, const float* __restrict__ c10,
    const float* __restrict__ h20, const float* __restrict__ c20,
    float* __restrict__ out, char* __restrict__ ws) {
  char* ctrl = ws;
  u32* linf  = (u32*)(ctrl + CT_LIN);
  u16* xbf   = (u16*)(ws + WS_XBF);
  u16* whh1f = (u16*)(ws + WS_WHH1);
  u16* wih1f = (u16*)(ws + WS_WIH1);
  u16* wih2f = (u16*)(ws + WS_WIH2);
  u16* whh2f = (u16*)(ws + WS_WHH2);
  u16* wlinf = (u16*)(ws + WS_WLIN);
  float* b1  = (float*)(ws + WS_B1);
  float* b2  = (float*)(ws + WS_B2);
  u32* h1s   = (u32*)(ws + WS_H1T);
  u32* h2s   = (u32*)(ws + WS_H2T);

  __shared__ __align__(16) u16 Ald[16 * 512];   // staged h tile (bf16, swizzled)
  __shared__ float exch[4 * 16 * 68];           // gate preact exchange

  const int tid = blockIdx.x * NTHR + threadIdx.x;

  // ---------------- phase 0: convert/pack (proven layouts) ----------------
  for (int c = tid; c < T_ * B_ * I_ / 8; c += NTOT)
    cvt8(xin + c * 8, xbf + c * 8);
  for (int c = tid; c < (1 << 17); c += NTOT) {
    int lane = c & 63, kt = (c >> 6) & 15, g = (c >> 10) & 3, n = c >> 12;
    int row = g * 512 + n * 16 + (lane & 15);
    int k   = kt * 32 + (lane >> 4) * 8;
    cvt8(Whh1 + row * 512 + k, whh1f + c * 8);
  }
  for (int c = tid; c < (1 << 16); c += NTOT) {
    int lane = c & 63, kt = (c >> 6) & 7, g = (c >> 9) & 3, n = c >> 11;
    int row = g * 512 + n * 16 + (lane & 15);
    int k   = kt * 32 + (lane >> 4) * 8;
    cvt8(Wih1 + row * 256 + k, wih1f + c * 8);
  }
  for (int c = tid; c < (1 << 17); c += NTOT) {
    int lane = c & 63, kt = (c >> 6) & 15, g = (c >> 10) & 3, n = c >> 12;
    int row = g * 512 + n * 16 + (lane & 15);
    int k   = kt * 32 + (lane >> 4) * 8;
    cvt8(Wih2 + row * 512 + k, wih2f + c * 8);
    cvt8(Whh2 + row * 512 + k, whh2f + c * 8);
  }
  for (int c = tid; c < (1 << 14); c += NTOT) {
    int lane = c & 63, kt = (c >> 6) & 15, nt = (c >> 10) & 1, l = c >> 11;
    int row = l * 32 + nt * 16 + (lane & 15);
    int k   = kt * 32 + (lane >> 4) * 8;
    cvt8(Wlin + row * 512 + k, wlinf + c * 8);
  }
  for (int i2 = tid; i2 < 2048; i2 += NTOT) {
    b1[i2] = bih1[i2] + bhh1[i2];
    b2[i2] = bih2[i2] + bhh2[i2];
  }
  // tagged rings: slot 0 <- initial h (tag 0); other slots <- 0xFFFF (never matches)
  for (int c = tid; c < (1 << 16); c += NTOT) {       // h1: 2 slots
    int slot = c >> 15, rem = c & 32767;
    int mtd = rem >> 13, r2 = rem & 8191, row = r2 >> 9, col = r2 & 511;
    u32 v = 0xFFFF0000u;
    if (slot == 0) v = (u32)f2bf(h10[(mtd * 16 + row) * 512 + col]);
    h1s[c] = v;
  }
  for (int c = tid; c < (1 << 17); c += NTOT) {       // h2: 4 slots
    int slot = c >> 15, rem = c & 32767;
    int mtd = rem >> 13, r2 = rem & 8191, row = r2 >> 9, col = r2 & 511;
    u32 v = 0xFFFF0000u;
    if (slot == 0) v = (u32)f2bf(h20[(mtd * 16 + row) * 512 + col]);
    h2s[c] = v;
  }

  gbar0((u32*)(ctrl + CT_B0), NBLK);   // B0: packed data + ring init at LLC

  const int lane = threadIdx.x & 63;
  const int w    = threadIdx.x >> 6;         // wave 0..7
  const int l15  = lane & 15;
  const int l31  = lane & 31;
  const int qd   = lane >> 4;
  const int prow = 2 * w + (lane >> 5);      // poll/stage row of the 16-row tile
  const int swz  = (prow & 7) << 4;          // LDS XOR swizzle for stage writes
  const int pb32 = prow * 512 + l31 * 16;    // u32 index within a (slot,mt) tile
  bool devok = true;                         // sticky: device-scope poll healthy

  // A-frag read: row=l15, K-chunk kt, sub-chunk qd (swizzle-consistent with stage)
  #define AFRAG(ktv) (*(const bf16x8*)((const char*)Ald + l15 * 1024 + \
                       (((ktv) * 64 + qd * 16) ^ ((l15 & 7) << 4))))
  #define STAGEA(pk) do { \
      u32x4 v0_ = {(pk)[0], (pk)[1], (pk)[2], (pk)[3]}; \
      u32x4 v1_ = {(pk)[4], (pk)[5], (pk)[6], (pk)[7]}; \
      char* ab_ = (char*)Ald + prow * 1024; \
      *(u32x4*)(ab_ + ((l31 * 32 +  0) ^ swz)) = v0_; \
      *(u32x4*)(ab_ + ((l31 * 32 + 16) ^ swz)) = v1_; \
    } while (0)

  if (blockIdx.x < NGB) {
    // ============== gate blocks: domain mt, 64 h-cols per block ==============
    const int mt = blockIdx.x >> 3;
    const int j  = blockIdx.x & 7;
    const int g  = w >> 1;                   // gate (i,f,g,o)
    const int half = w & 1;
    const int nt0 = j * 4 + half * 2;        // global 16-col tiles nt0, nt0+1

    bf16x8 Wr0[16], Wr1[16];                 // recurrent weights
    #pragma unroll
    for (int kt = 0; kt < 16; kt++) {
      Wr0[kt] = ldg8(whh1f + ((size_t)((nt0 + 0) * 4 + g) * 16 + kt) * 512 + lane * 8);
      Wr1[kt] = ldg8(whh1f + ((size_t)((nt0 + 1) * 4 + g) * 16 + kt) * 512 + lane * 8);
    }
    const float bg0 = b1[g * 512 + (nt0 + 0) * 16 + l15];
    const float bg1 = b1[g * 512 + (nt0 + 1) * 16 + l15];

    const int hcol = j * 64 + lane;          // elementwise: rows 2w,2w+1 col=lane
    float c0v = c10[(mt * 16 + 2 * w + 0) * 512 + hcol];
    float c1v = c10[(mt * 16 + 2 * w + 1) * 512 + hcol];

    const u16* wx0 = wih1f + ((size_t)((nt0 + 0) * 4 + g) * 8) * 512 + lane * 8;
    const u16* wx1 = wih1f + ((size_t)((nt0 + 1) * 4 + g) * 8) * 512 + lane * 8;
    const int axoff = (mt * 16 + l15) * 256 + qd * 8;
    const int sobase = (2 * w) * 512 + j * 64 + lane;

    f32x4 p0, p1;                            // x-projection (+bias) for step t
    {
      p0 = f32x4{bg0, bg0, bg0, bg0};
      p1 = f32x4{bg1, bg1, bg1, bg1};
      const u16* xr = xbf + axoff;
      #pragma unroll
      for (int kt = 0; kt < 8; kt++) {
        bf16x8 ax = ldg8(xr + kt * 32);
        p0 = MFMA16(ax, ldg8(wx0 + kt * 512), p0);
        p1 = MFMA16(ax, ldg8(wx1 + kt * 512), p1);
      }
    }

    // -------- encoder --------
    for (int t = 0; t < T_; t++) {
      u32 pk[8];
      pollTile<false, 0>(h1s + (size_t)((t & 1) * 4 + mt) * 8192 + pb32,
                         (u32)t, linf, 0, pk, devok);
      STAGEA(pk);
      __syncthreads();
      f32x4 a0 = p0, a1 = p1;
      f32x4 a2 = {0.f, 0.f, 0.f, 0.f}, a3 = {0.f, 0.f, 0.f, 0.f};
      #pragma unroll
      for (int kt = 0; kt < 16; kt += 2) {
        bf16x8 af0 = AFRAG(kt), af1 = AFRAG(kt + 1);
        a0 = MFMA16(af0, Wr0[kt], a0);
        a1 = MFMA16(af0, Wr1[kt], a1);
        a2 = MFMA16(af1, Wr0[kt + 1], a2);
        a3 = MFMA16(af1, Wr1[kt + 1], a3);
      }
      a0 += a2; a1 += a3;
      #pragma unroll
      for (int r = 0; r < 4; r++) {
        exch[g * 1088 + (qd * 4 + r) * 68 + half * 32 +  0 + l15] = a0[r];
        exch[g * 1088 + (qd * 4 + r) * 68 + half * 32 + 16 + l15] = a1[r];
      }
      __syncthreads();
      {
        u32* so = h1s + (size_t)(((t + 1) & 1) * 4 + mt) * 8192 + sobase;
        #pragma unroll
        for (int rr = 0; rr < 2; rr++) {
          int rw = 2 * w + rr;
          float gi = exch[0 * 1088 + rw * 68 + lane];
          float gf = exch[1 * 1088 + rw * 68 + lane];
          float gg = exch[2 * 1088 + rw * 68 + lane];
          float go = exch[3 * 1088 + rw * 68 + lane];
          float cc = rr ? c1v : c0v;
          cc = sigm(gf) * cc + sigm(gi) * tanh_(gg);
          if (rr) c1v = cc; else c0v = cc;
          float hv = sigm(go) * tanh_(cc);
          ast32(so + rr * 512, (u32)f2bf(hv) | ((u32)(t + 1) << 16));
        }
      }
      // x-projection for t+1 (overlaps store drain / next poll)
      if (t + 1 < T_) {
        p0 = f32x4{bg0, bg0, bg0, bg0};
        p1 = f32x4{bg1, bg1, bg1, bg1};
        const u16* xr = xbf + (size_t)(t + 1) * (B_ * I_) + axoff;
        #pragma unroll
        for (int kt = 0; kt < 8; kt++) {
          bf16x8 ax = ldg8(xr + kt * 32);
          p0 = MFMA16(ax, ldg8(wx0 + kt * 512), p0);
          p1 = MFMA16(ax, ldg8(wx1 + kt * 512), p1);
        }
      }
    }

    // -------- transition: q = b2 + h1{T} @ Wih2^T ; swap weights to LSTM2 ----
    f32x4 q0, q1;
    {
      u32 pk[8];
      pollTile<false, 0>(h1s + (size_t)(0 * 4 + mt) * 8192 + pb32,  // T even -> slot 0
                         (u32)T_, linf, 0, pk, devok);
      STAGEA(pk);
      __syncthreads();
      const float b20 = b2[g * 512 + (nt0 + 0) * 16 + l15];
      const float b21 = b2[g * 512 + (nt0 + 1) * 16 + l15];
      q0 = f32x4{b20, b20, b20, b20};
      q1 = f32x4{b21, b21, b21, b21};
      #pragma unroll
      for (int kt = 0; kt < 16; kt++) {
        bf16x8 af = AFRAG(kt);
        q0 = MFMA16(af, ldg8(wih2f + ((size_t)((nt0 + 0) * 4 + g) * 16 + kt) * 512 + lane * 8), q0);
        q1 = MFMA16(af, ldg8(wih2f + ((size_t)((nt0 + 1) * 4 + g) * 16 + kt) * 512 + lane * 8), q1);
      }
      #pragma unroll
      for (int kt = 0; kt < 16; kt++) {
        Wr0[kt] = ldg8(whh2f + ((size_t)((nt0 + 0) * 4 + g) * 16 + kt) * 512 + lane * 8);
        Wr1[kt] = ldg8(whh2f + ((size_t)((nt0 + 1) * 4 + g) * 16 + kt) * 512 + lane * 8);
      }
      c0v = c20[(mt * 16 + 2 * w + 0) * 512 + hcol];
      c1v = c20[(mt * 16 + 2 * w + 1) * 512 + hcol];
      __syncthreads();   // Ald reads done before decoder's first stage
    }

    // -------- decoder --------
    for (int t = 0; t < T_; t++) {
      u32 pk[8];
      const u32* lfp = linf + mt * 2 + (lane & 1);
      const int ltgt = (lane < 2) ? (t - 3) : -1;     // ring back-pressure, in-round
      pollTile<true, 0>(h2s + (size_t)((t & 3) * 4 + mt) * 8192 + pb32,
                        (u32)t, lfp, ltgt, pk, devok);
      STAGEA(pk);
      __syncthreads();
      f32x4 a0 = q0, a1 = q1;
      f32x4 a2 = {0.f, 0.f, 0.f, 0.f}, a3 = {0.f, 0.f, 0.f, 0.f};
      #pragma unroll
      for (int kt = 0; kt < 16; kt += 2) {
        bf16x8 af0 = AFRAG(kt), af1 = AFRAG(kt + 1);
        a0 = MFMA16(af0, Wr0[kt], a0);
        a1 = MFMA16(af0, Wr1[kt], a1);
        a2 = MFMA16(af1, Wr0[kt + 1], a2);
        a3 = MFMA16(af1, Wr1[kt + 1], a3);
      }
      a0 += a2; a1 += a3;
      #pragma unroll
      for (int r = 0; r < 4; r++) {
        exch[g * 1088 + (qd * 4 + r) * 68 + half * 32 +  0 + l15] = a0[r];
        exch[g * 1088 + (qd * 4 + r) * 68 + half * 32 + 16 + l15] = a1[r];
      }
      __syncthreads();
      {
        u32* so = h2s + (size_t)(((t + 1) & 3) * 4 + mt) * 8192 + sobase;
        #pragma unroll
        for (int rr = 0; rr < 2; rr++) {
          int rw = 2 * w + rr;
          float gi = exch[0 * 1088 + rw * 68 + lane];
          float gf = exch[1 * 1088 + rw * 68 + lane];
          float gg = exch[2 * 1088 + rw * 68 + lane];
          float go = exch[3 * 1088 + rw * 68 + lane];
          float cc = rr ? c1v : c0v;
          cc = sigm(gf) * cc + sigm(gi) * tanh_(gg);
          if (rr) c1v = cc; else c0v = cc;
          float hv = sigm(go) * tanh_(cc);
          ast32(so + rr * 512, (u32)f2bf(hv) | ((u32)(t + 1) << 16));
        }
      }
    }
  } else {
    // ============== linear blocks: (mt, q), wave = out col-tile ==============
    const int b  = blockIdx.x - NGB;
    const int mt = b >> 1, qq = b & 1;
    const int to = qq * 8 + w;               // out col-tile 0..15
    bf16x8 Wl[16];
    #pragma unroll
    for (int kt = 0; kt < 16; kt++)
      Wl[kt] = ldg8(wlinf + ((size_t)to * 16 + kt) * 512 + lane * 8);
    const float bl = blin[to * 16 + l15];
    u32* lfp = linf + mt * 2 + qq;

    // out[s] = W_lin . h2{s+1}
    for (int s = 0; s < T_; s++) {
      u32 pk[8];
      pollTile<false, 2>(h2s + (size_t)(((s + 1) & 3) * 4 + mt) * 8192 + pb32,
                         (u32)(s + 1), linf, 0, pk, devok);
      STAGEA(pk);
      __syncthreads();
      if (threadIdx.x == 0) ast32(lfp, (u32)(s + 1));   // release ring slot
      f32x4 o = {bl, bl, bl, bl};
      #pragma unroll
      for (int kt = 0; kt < 16; kt++) {
        bf16x8 af = AFRAG(kt);
        o = MFMA16(af, Wl[kt], o);
      }
      float* op = out + ((size_t)s * 64 + mt * 16 + qd * 4) * 256 + to * 16 + l15;
      #pragma unroll
      for (int r = 0; r < 4; r++) op[(size_t)r * 256] = o[r];
      __syncthreads();                       // Ald reads done before next stage
    }
  }
  #undef AFRAG
  #undef STAGEA
}

extern "C" void kernel_launch(void* const* d_in, const int* in_sizes, int n_in,
                              void* d_out, int out_size, void* d_ws, size_t ws_size,
                              hipStream_t stream) {
  (void)in_sizes; (void)n_in; (void)out_size; (void)ws_size;
  const float* xin  = (const float*)d_in[0];
  const float* Wih1 = (const float*)d_in[1];
  const float* Whh1 = (const float*)d_in[2];
  const float* bih1 = (const float*)d_in[3];
  const float* bhh1 = (const float*)d_in[4];
  const float* Wih2 = (const float*)d_in[5];
  const float* Whh2 = (const float*)d_in[6];
  const float* bih2 = (const float*)d_in[7];
  const float* bhh2 = (const float*)d_in[8];
  const float* Wlin = (const float*)d_in[9];
  const float* blin = (const float*)d_in[10];
  const float* h10  = (const float*)d_in[11];
  const float* c10  = (const float*)d_in[12];
  const float* h20  = (const float*)d_in[13];
  const float* c20  = (const float*)d_in[14];
  float* out = (float*)d_out;
  char* ws   = (char*)d_ws;

  init_cnt<<<dim3(1), dim3(256), 0, stream>>>(ws);

  void* args[] = { (void*)&xin, (void*)&Wih1, (void*)&Whh1, (void*)&bih1, (void*)&bhh1,
                   (void*)&Wih2, (void*)&Whh2, (void*)&bih2, (void*)&bhh2,
                   (void*)&Wlin, (void*)&blin, (void*)&h10, (void*)&c10,
                   (void*)&h20, (void*)&c20, (void*)&out, (void*)&ws };
  hipLaunchCooperativeKernel((void*)lstm_ae_kernel, dim3(NBLK), dim3(NTHR),
                             args, 0, stream);
}